// Round 1
// baseline (479.226 us; speedup 1.0000x reference)
//
#include <hip/hip_runtime.h>
#include <math.h>

// Problem constants
#define NPIX   131072      // B*H*W = 32*64*64
#define KEMB   512
#define DDIM   64
#define HW     4096        // H*W
#define BSTRIDE 262144     // C*H*W

// d_out flat layout (float32): [loss(1) | out(8388608) | perplexity(1) | indices(131072)]
#define OUT_OFF  1
#define PERP_OFF 8388609
#define IDX_OFF  8388610

typedef __attribute__((ext_vector_type(8))) short bf16x8;   // 8 bf16 = 4 VGPRs (MFMA A/B frag)
typedef __attribute__((ext_vector_type(4))) float f32x4;    // MFMA C/D frag

__device__ __forceinline__ unsigned short bf16_rtne(float f) {
    unsigned int u = __float_as_uint(f);
    u += 0x7FFFu + ((u >> 16) & 1u);
    return (unsigned short)(u >> 16);
}
__device__ __forceinline__ float bf16_to_f(unsigned short h) {
    return __uint_as_float(((unsigned int)h) << 16);
}

// 6 split-products per k-step: hh, hm, mh, hl, lh, mm (R5..R11 order — passed)
#define MFMA_STEP(AH, AM, AL, XH, XM, XL, ACC) \
    ACC = __builtin_amdgcn_mfma_f32_16x16x32_bf16(AH, XH, ACC, 0, 0, 0); \
    ACC = __builtin_amdgcn_mfma_f32_16x16x32_bf16(AH, XM, ACC, 0, 0, 0); \
    ACC = __builtin_amdgcn_mfma_f32_16x16x32_bf16(AM, XH, ACC, 0, 0, 0); \
    ACC = __builtin_amdgcn_mfma_f32_16x16x32_bf16(AH, XL, ACC, 0, 0, 0); \
    ACC = __builtin_amdgcn_mfma_f32_16x16x32_bf16(AL, XH, ACC, 0, 0, 0); \
    ACC = __builtin_amdgcn_mfma_f32_16x16x32_bf16(AM, XM, ACC, 0, 0, 0);

// ws layout: [0,2048) int counts | [2048,4096) float hnorms | [4096] loss |
//            [4160] done_ctr | [8192,73728) ebh_t (tiled frag order, 64KB) |
//            [73728,204800) ebml (tile-interleaved m+l, 128KB)
//
// ebh_t: ushort idx = ct*1024 + ks*512 + (quad*16+col)*8 + j  (frag-linear, so
//        vq_main stages it with a straight linear copy).
// ebml:  ushort idx = ct*2048 + col*128 + ks*64 + (m:0 / l:32) + quad*8 + j
//        => per lane, tile fragments at byte base + {0, 64, 128, 192}, all four
//        within one 256-B run (one L1 line pair per lane, 4KB per tile).
__global__ void vq_init(const float* __restrict__ emb, int* __restrict__ counts,
                        float* __restrict__ hnorms, float* __restrict__ loss_acc,
                        int* __restrict__ done_ctr,
                        unsigned short* __restrict__ ebh_t,
                        unsigned short* __restrict__ ebml) {
    const int k = blockIdx.x;             // code
    const int c = threadIdx.x;            // channel
    const int ct = k >> 4, col = k & 15;
    const int ks = c >> 5, quad = (c >> 3) & 3, j = c & 7;
    float x = emb[k * DDIM + c];
    unsigned short h = bf16_rtne(x);
    float r1 = x - bf16_to_f(h);          // exact (Sterbenz)
    unsigned short m = bf16_rtne(r1);
    float r2 = r1 - bf16_to_f(m);         // exact
    unsigned short l = bf16_rtne(r2);
    ebh_t[ct * 1024 + ks * 512 + (quad * 16 + col) * 8 + j] = h;
    const int mb = ct * 2048 + col * 128 + ks * 64 + quad * 8 + j;
    ebml[mb]      = m;
    ebml[mb + 32] = l;
    float s = x * x;
#pragma unroll
    for (int off = 1; off <= 32; off <<= 1) s += __shfl_xor(s, off, 64);
    if (c == 0) {
        hnorms[k] = 0.5f * s;
        counts[k] = 0;
        if (k == 0) { *loss_acc = 0.f; *done_ctr = 0; }
    }
}

// 512 blocks x 1024 threads => 2 blocks/CU, 32 waves/CU (LDS 68KB, VGPR cap 64).
// Only the h-table lives in LDS; m+l fragments stream from the fused L1/L2-hot
// ebml table per tile. Each wave owns 16 pixels (one 16x16 output tile, single
// acc chain). K-loop stays barrier-free. vq_fin is fused via last-block ticket.
__global__ __launch_bounds__(1024, 8) void vq_main(
    const float* __restrict__ in, const float* __restrict__ emb,
    const unsigned short* __restrict__ ebh_t, const unsigned short* __restrict__ ebml,
    const float* __restrict__ hnorms, int* __restrict__ counts,
    float* __restrict__ loss_acc, int* __restrict__ done_ctr,
    float* __restrict__ dout)
{
    __shared__ __align__(16) unsigned short ebh_l[KEMB * DDIM];  // 64 KB
    __shared__ __align__(16) float hn_lds[KEMB];                 // 2 KB
    __shared__ int hist[KEMB];                                   // 2 KB
    __shared__ float part[8];
    __shared__ int lastflag;

    const int t    = threadIdx.x;         // 0..1023
    const int lane = t & 63;
    const int wv   = t >> 6;              // wave id 0..15
    const int quad = lane >> 4;
    const int col  = lane & 15;
    const int b    = blockIdx.x >> 4;                        // 16 blocks per image
    const int p0   = ((blockIdx.x & 15) << 8) | (wv << 4);   // first of this wave's 16 px
    const float* xb = in + b * BSTRIDE;

    if (t < KEMB) hist[t] = 0;
    if (t < 128) ((float4*)hn_lds)[t] = ((const float4*)hnorms)[t];

    // ---- Stage h table into LDS: pure linear 64KB copy (table is pre-tiled).
#pragma unroll
    for (int i = 0; i < 4; ++i) {
        const int f = (t + i * 1024) * 8;
        *(bf16x8*)&ebh_l[f] = *(const bf16x8*)(ebh_t + f);
    }

    // ---- Build x B-fragments: B[n=col][k=quad*8+j], xf[split][kstep]
    bf16x8 xf[3][2];
#pragma unroll
    for (int s = 0; s < 2; ++s) {
        const int ppb = p0 + col;
        const int c0  = s * 32 + quad * 8;
        bf16x8 vh, vm, vl;
#pragma unroll
        for (int j = 0; j < 8; ++j) {
            float x = xb[(c0 + j) * HW + ppb];
            unsigned short h = bf16_rtne(x);
            float r1 = x - bf16_to_f(h);
            unsigned short m = bf16_rtne(r1);
            float r2 = r1 - bf16_to_f(m);
            unsigned short l = bf16_rtne(r2);
            vh[j] = (short)h; vm[j] = (short)m; vl[j] = (short)l;
        }
        xf[0][s] = vh; xf[1][s] = vm; xf[2][s] = vl;
    }

    __syncthreads();   // staging done; K-loop below is barrier-free

    // ---- K-loop over 32 code tiles (m+l fragments streamed from L1/L2)
    float v1 = 3.402823466e38f, v2 = 3.402823466e38f;
    int   k1 = 0, k2 = 0;
    const char* ap = (const char*)ebml + col * 256 + quad * 16;

    for (int ct = 0; ct < 32; ++ct) {
        const bf16x8 Am0 = *(const bf16x8*)(ap);
        const bf16x8 Al0 = *(const bf16x8*)(ap + 64);
        const bf16x8 Am1 = *(const bf16x8*)(ap + 128);
        const bf16x8 Al1 = *(const bf16x8*)(ap + 192);
        ap += 4096;

        const int base = ct * 1024 + lane * 8;
        const bf16x8 Ah0 = *(const bf16x8*)&ebh_l[base];
        const bf16x8 Ah1 = *(const bf16x8*)&ebh_l[base + 512];

        f32x4 acc = (f32x4){0.f, 0.f, 0.f, 0.f};
        MFMA_STEP(Ah0, Am0, Al0, xf[0][0], xf[1][0], xf[2][0], acc)
        MFMA_STEP(Ah1, Am1, Al1, xf[0][1], xf[1][1], xf[2][1], acc)

        const f32x4 hn = *(const f32x4*)&hn_lds[ct * 16 + quad * 4];
#pragma unroll
        for (int r = 0; r < 4; ++r) {
            const int kk = ct * 16 + quad * 4 + r;
            float sc = hn[r] - acc[r];
            if (sc < v1) { v2 = v1; k2 = k1; v1 = sc; k1 = kk; }
            else if (sc < v2) { v2 = sc; k2 = kk; }
        }
    }

    // Cross-quad top-2 merge (lanes l, l^16, l^32 share pixel-col) — R6 verbatim
#pragma unroll
    for (int off = 16; off <= 32; off <<= 1) {
        float w1 = __shfl_xor(v1, off, 64); int j1 = __shfl_xor(k1, off, 64);
        float w2 = __shfl_xor(v2, off, 64); int j2 = __shfl_xor(k2, off, 64);
        bool aF = (v1 < w1) || (v1 == w1 && k1 < j1);
        float t1 = aF ? v1 : w1;  int u1 = aF ? k1 : j1;
        float tl = aF ? w1 : v1;  int ul = aF ? j1 : k1;      // loser of firsts
        bool bS = (v2 < w2) || (v2 == w2 && k2 < j2);
        float tc = bS ? v2 : w2;  int uc = bS ? k2 : j2;      // better of seconds
        bool lS = (tl < tc) || (tl == tc && ul < uc);
        v1 = t1; k1 = u1;
        v2 = lS ? tl : tc; k2 = lS ? ul : uc;
    }

    // Pixel q = lane&15; all 4 quad-lanes of a pixel hold the merged top-2.
    const int q    = lane & 15;
    const int pp   = p0 + q;
    const int kA   = k1, kB = k2;

    // Exact fp32 rescore, split: lanes<32 score kA, lanes>=32 score kB.
    // Streaming x loads — per-pixel op chain bitwise == previous passing kernel.
    const int kMine = (lane < 32) ? kA : kB;
    const float4* eM = (const float4*)(emb + kMine * DDIM);
    float a0 = hn_lds[kMine], a1 = 0.f, a2 = 0.f, a3 = 0.f;
#pragma unroll
    for (int i = 0; i < 16; ++i) {
        float4 ea = eM[i];
        const int c = i * 4;
        float x0 = xb[(c + 0) * HW + pp];
        float x1 = xb[(c + 1) * HW + pp];
        float x2 = xb[(c + 2) * HW + pp];
        float x3 = xb[(c + 3) * HW + pp];
        a0 = fmaf(-x0, ea.x, a0);
        a1 = fmaf(-x1, ea.y, a1);
        a2 = fmaf(-x2, ea.z, a2);
        a3 = fmaf(-x3, ea.w, a3);
    }
    const float dMine = (a0 + a1) + (a2 + a3);
    const float dOth  = __shfl_xor(dMine, 32, 64);
    const float dA = (lane < 32) ? dMine : dOth;
    const float dB = (lane < 32) ? dOth  : dMine;
    const int myk = (dB < dA || (dB == dA && kB < kA)) ? kB : kA;

    float lsum = 0.f;
    if (lane < 16) {
        dout[IDX_OFF + b * HW + pp] = (float)myk;
        atomicAdd(&hist[myk], 1);
        const float4* qrow = (const float4*)(emb + myk * DDIM);
        float* ob = dout + OUT_OFF + b * BSTRIDE;
#pragma unroll
        for (int i = 0; i < 16; ++i) {
            float4 qv = qrow[i];
            const int c = i * 4;
            float x0 = xb[(c + 0) * HW + pp];   // L1-warm reload (just read above)
            float x1 = xb[(c + 1) * HW + pp];
            float x2 = xb[(c + 2) * HW + pp];
            float x3 = xb[(c + 3) * HW + pp];
            float d0 = qv.x - x0;
            float d1 = qv.y - x1;
            float d2 = qv.z - x2;
            float d3 = qv.w - x3;
            lsum += d0 * d0 + d1 * d1 + d2 * d2 + d3 * d3;
            ob[(c + 0) * HW + pp] = x0 + d0;    // reference rounding: x + (q - x)
            ob[(c + 1) * HW + pp] = x1 + d1;
            ob[(c + 2) * HW + pp] = x2 + d2;
            ob[(c + 3) * HW + pp] = x3 + d3;
        }
    }
    for (int off = 32; off > 0; off >>= 1) lsum += __shfl_down(lsum, off, 64);
    if (lane == 0) atomicAdd(loss_acc, lsum);

    __syncthreads();
    if (t < KEMB) {
        int v = hist[t];
        if (v) atomicAdd(&counts[t], v);
    }

    // ---- Fused finalize: last block to arrive computes perplexity + loss.
    __threadfence();
    __syncthreads();
    if (t == 0) lastflag = (atomicAdd(done_ctr, 1) == 511) ? 1 : 0;
    __syncthreads();
    if (lastflag) {
        if (t < KEMB) {
            int cnt = atomicAdd(&counts[t], 0);   // device-coherent read
            float pa = (float)cnt / (float)NPIX;
            float v = pa * logf(pa + 1e-10f);
#pragma unroll
            for (int off = 1; off <= 32; off <<= 1) v += __shfl_xor(v, off, 64);
            if ((t & 63) == 0) part[t >> 6] = v;
        }
        __syncthreads();
        if (t == 0) {
            float s = 0.f;
#pragma unroll
            for (int i = 0; i < 8; ++i) s += part[i];
            dout[PERP_OFF] = expf(-s);
            dout[0] = 0.25f * atomicAdd(loss_acc, 0.0f) / 8388608.0f;
        }
    }
}

extern "C" void kernel_launch(void* const* d_in, const int* in_sizes, int n_in,
                              void* d_out, int out_size, void* d_ws, size_t ws_size,
                              hipStream_t stream) {
    const float* in  = (const float*)d_in[0];   // 8388608 elems
    const float* emb = (const float*)d_in[1];   // 32768 elems
    float* dout = (float*)d_out;
    int*   counts   = (int*)d_ws;
    float* hnorms   = (float*)((char*)d_ws + 2048);
    float* loss_acc = (float*)((char*)d_ws + 4096);
    int*   done_ctr = (int*)((char*)d_ws + 4160);
    unsigned short* ebh_t = (unsigned short*)((char*)d_ws + 8192);
    unsigned short* ebml  = ebh_t + KEMB * DDIM;   // 128 KB fused m+l table

    vq_init<<<512, 64, 0, stream>>>(emb, counts, hnorms, loss_acc, done_ctr, ebh_t, ebml);
    vq_main<<<512, 1024, 0, stream>>>(in, emb, ebh_t, ebml, hnorms, counts, loss_acc, done_ctr, dout);
}

// Round 2
// 385.300 us; speedup vs baseline: 1.2438x; 1.2438x over previous
//
#include <hip/hip_runtime.h>
#include <hip/hip_fp16.h>
#include <math.h>

// Problem constants
#define NPIX   131072      // B*H*W = 32*64*64
#define KEMB   512
#define DDIM   64
#define HW     4096        // H*W
#define BSTRIDE 262144     // C*H*W

// d_out flat layout (float32): [loss(1) | out(8388608) | perplexity(1) | indices(131072)]
#define OUT_OFF  1
#define PERP_OFF 8388609
#define IDX_OFF  8388610

typedef __attribute__((ext_vector_type(8))) short bf16x8;      // 16B staging copy
typedef __attribute__((ext_vector_type(8))) _Float16 f16x8;    // MFMA A/B frag (4 VGPRs)
typedef __attribute__((ext_vector_type(4))) float f32x4;       // MFMA C/D frag

// ws layout: [0,2048) int counts | [2048,4096) float hnorms | [4096] loss |
//            [4160] done_ctr | [8192,73728) eh_t (f16 high, frag-linear, 64KB) |
//            [73728,139264) el_t (f16 low pre-scaled by 2^11, frag-linear, 64KB)
//
// frag-linear: ushort idx = ct*1024 + ks*512 + (quad*16+col)*8 + j, so vq_main
// stages eh with a straight linear copy and streams el at ap + {0,1024} bytes.
//
// 2-split f16 scheme: x = h + l/2048 + r, |r| <= 2^-22|x|.  Pre-scaling l by
// 2^11 (exact pow2) keeps the residual in f16 NORMAL range (|l'| ~ |x|), so no
// dependence on MFMA f16-denormal behavior.  Products kept: hh + (h*l' + l'*h)/2048.
// Dropped terms ~3*2^-22 * ||x||*||e|| ~ 3e-5 absolute on distances; the exact
// fp32 top-2 rescore (verbatim from the passing kernel) decides the winner, so
// a wrong result needs a 3-way distance tie within ~6e-5 — measure-zero here.
__global__ void vq_init(const float* __restrict__ emb, int* __restrict__ counts,
                        float* __restrict__ hnorms, float* __restrict__ loss_acc,
                        int* __restrict__ done_ctr,
                        unsigned short* __restrict__ eh_t,
                        unsigned short* __restrict__ el_t) {
    const int k = blockIdx.x;             // code
    const int c = threadIdx.x;            // channel
    const int ct = k >> 4, col = k & 15;
    const int ks = c >> 5, quad = (c >> 3) & 3, j = c & 7;
    float x = emb[k * DDIM + c];
    _Float16 h = (_Float16)x;             // v_cvt_f16_f32, RTNE
    float r1 = x - (float)h;              // exact (Sterbenz)
    _Float16 l = (_Float16)(r1 * 2048.0f);
    const int dst = ct * 1024 + ks * 512 + (quad * 16 + col) * 8 + j;
    ((_Float16*)eh_t)[dst] = h;
    ((_Float16*)el_t)[dst] = l;
    float s = x * x;
#pragma unroll
    for (int off = 1; off <= 32; off <<= 1) s += __shfl_xor(s, off, 64);
    if (c == 0) {
        hnorms[k] = 0.5f * s;
        counts[k] = 0;
        if (k == 0) { *loss_acc = 0.f; *done_ctr = 0; }
    }
}

// 512 blocks x 1024 threads => 2 blocks/CU, 32 waves/CU (LDS 68KB, 64-reg cap).
// Only the f16 h-table lives in LDS; the scaled-l fragments stream from the
// L2-hot 64KB el table (no prefetch regs — 8 waves/SIMD hide the latency).
// Each wave owns 16 pixels, one (acc0,acc1) pair. K-loop stays barrier-free.
__global__ __launch_bounds__(1024, 8) void vq_main(
    const float* __restrict__ in, const float* __restrict__ emb,
    const unsigned short* __restrict__ eh_t, const unsigned short* __restrict__ el_t,
    const float* __restrict__ hnorms, int* __restrict__ counts,
    float* __restrict__ loss_acc, int* __restrict__ done_ctr,
    float* __restrict__ dout)
{
    __shared__ __align__(16) unsigned short ebh_l[KEMB * DDIM];  // 64 KB
    __shared__ __align__(16) float hn_lds[KEMB];                 // 2 KB
    __shared__ int hist[KEMB];                                   // 2 KB
    __shared__ float part[8];
    __shared__ int lastflag;

    const int t    = threadIdx.x;         // 0..1023
    const int lane = t & 63;
    const int wv   = t >> 6;              // wave id 0..15
    const int quad = lane >> 4;
    const int col  = lane & 15;
    const int b    = blockIdx.x >> 4;                        // 16 blocks per image
    const int p0   = ((blockIdx.x & 15) << 8) | (wv << 4);   // first of this wave's 16 px
    const float* xb = in + b * BSTRIDE;

    if (t < KEMB) hist[t] = 0;
    if (t < 128) ((float4*)hn_lds)[t] = ((const float4*)hnorms)[t];

    // ---- Stage h table into LDS: pure linear 64KB copy (table is pre-tiled).
#pragma unroll
    for (int i = 0; i < 4; ++i) {
        const int f = (t + i * 1024) * 8;
        *(bf16x8*)&ebh_l[f] = *(const bf16x8*)(eh_t + f);
    }

    // ---- Build x B-fragments: B[n=col][k=quad*8+j], splits h / scaled-l
    f16x8 xh[2], xl[2];
#pragma unroll
    for (int s = 0; s < 2; ++s) {
        const int ppb = p0 + col;
        const int c0  = s * 32 + quad * 8;
        f16x8 vh, vl;
#pragma unroll
        for (int j = 0; j < 8; ++j) {
            float x = xb[(c0 + j) * HW + ppb];
            _Float16 h = (_Float16)x;
            float r1 = x - (float)h;
            vh[j] = h;
            vl[j] = (_Float16)(r1 * 2048.0f);
        }
        xh[s] = vh; xl[s] = vl;
    }

    __syncthreads();   // staging done; K-loop below is barrier-free

    // ---- K-loop over 32 code tiles (scaled-l fragments streamed from L1/L2)
    float v1 = 3.402823466e38f, v2 = 3.402823466e38f;
    int   k1 = 0, k2 = 0;
    const char* ap = (const char*)el_t + lane * 16;

    for (int ct = 0; ct < 32; ++ct) {
        const f16x8 Al0 = *(const f16x8*)(ap);
        const f16x8 Al1 = *(const f16x8*)(ap + 1024);
        ap += 2048;

        const int base = ct * 1024 + lane * 8;
        const f16x8 Ah0 = *(const f16x8*)&ebh_l[base];
        const f16x8 Ah1 = *(const f16x8*)&ebh_l[base + 512];

        f32x4 acc0 = (f32x4){0.f, 0.f, 0.f, 0.f};   // hh
        f32x4 acc1 = (f32x4){0.f, 0.f, 0.f, 0.f};   // 2^11 * (h*l + l*h)
        acc0 = __builtin_amdgcn_mfma_f32_16x16x32_f16(Ah0, xh[0], acc0, 0, 0, 0);
        acc1 = __builtin_amdgcn_mfma_f32_16x16x32_f16(Ah0, xl[0], acc1, 0, 0, 0);
        acc1 = __builtin_amdgcn_mfma_f32_16x16x32_f16(Al0, xh[0], acc1, 0, 0, 0);
        acc0 = __builtin_amdgcn_mfma_f32_16x16x32_f16(Ah1, xh[1], acc0, 0, 0, 0);
        acc1 = __builtin_amdgcn_mfma_f32_16x16x32_f16(Ah1, xl[1], acc1, 0, 0, 0);
        acc1 = __builtin_amdgcn_mfma_f32_16x16x32_f16(Al1, xh[1], acc1, 0, 0, 0);

        const f32x4 hn = *(const f32x4*)&hn_lds[ct * 16 + quad * 4];
#pragma unroll
        for (int r = 0; r < 4; ++r) {
            const int kk = ct * 16 + quad * 4 + r;
            float sc = hn[r] - (acc0[r] + acc1[r] * 4.8828125e-4f);  // + acc1/2048
            if (sc < v1) { v2 = v1; k2 = k1; v1 = sc; k1 = kk; }
            else if (sc < v2) { v2 = sc; k2 = kk; }
        }
    }

    // Cross-quad top-2 merge (lanes l, l^16, l^32 share pixel-col) — R6 verbatim
#pragma unroll
    for (int off = 16; off <= 32; off <<= 1) {
        float w1 = __shfl_xor(v1, off, 64); int j1 = __shfl_xor(k1, off, 64);
        float w2 = __shfl_xor(v2, off, 64); int j2 = __shfl_xor(k2, off, 64);
        bool aF = (v1 < w1) || (v1 == w1 && k1 < j1);
        float t1 = aF ? v1 : w1;  int u1 = aF ? k1 : j1;
        float tl = aF ? w1 : v1;  int ul = aF ? j1 : k1;      // loser of firsts
        bool bS = (v2 < w2) || (v2 == w2 && k2 < j2);
        float tc = bS ? v2 : w2;  int uc = bS ? k2 : j2;      // better of seconds
        bool lS = (tl < tc) || (tl == tc && ul < uc);
        v1 = t1; k1 = u1;
        v2 = lS ? tl : tc; k2 = lS ? ul : uc;
    }

    // Pixel q = lane&15; all 4 quad-lanes of a pixel hold the merged top-2.
    const int q    = lane & 15;
    const int pp   = p0 + q;
    const int kA   = k1, kB = k2;

    // Exact fp32 rescore, split: lanes<32 score kA, lanes>=32 score kB.
    // Streaming x loads — per-pixel op chain bitwise == previous passing kernel.
    const int kMine = (lane < 32) ? kA : kB;
    const float4* eM = (const float4*)(emb + kMine * DDIM);
    float a0 = hn_lds[kMine], a1 = 0.f, a2 = 0.f, a3 = 0.f;
#pragma unroll
    for (int i = 0; i < 16; ++i) {
        float4 ea = eM[i];
        const int c = i * 4;
        float x0 = xb[(c + 0) * HW + pp];
        float x1 = xb[(c + 1) * HW + pp];
        float x2 = xb[(c + 2) * HW + pp];
        float x3 = xb[(c + 3) * HW + pp];
        a0 = fmaf(-x0, ea.x, a0);
        a1 = fmaf(-x1, ea.y, a1);
        a2 = fmaf(-x2, ea.z, a2);
        a3 = fmaf(-x3, ea.w, a3);
    }
    const float dMine = (a0 + a1) + (a2 + a3);
    const float dOth  = __shfl_xor(dMine, 32, 64);
    const float dA = (lane < 32) ? dMine : dOth;
    const float dB = (lane < 32) ? dOth  : dMine;
    const int myk = (dB < dA || (dB == dA && kB < kA)) ? kB : kA;

    float lsum = 0.f;
    if (lane < 16) {
        dout[IDX_OFF + b * HW + pp] = (float)myk;
        atomicAdd(&hist[myk], 1);
        const float4* qrow = (const float4*)(emb + myk * DDIM);
        float* ob = dout + OUT_OFF + b * BSTRIDE;
#pragma unroll
        for (int i = 0; i < 16; ++i) {
            float4 qv = qrow[i];
            const int c = i * 4;
            float x0 = xb[(c + 0) * HW + pp];   // L1-warm reload (just read above)
            float x1 = xb[(c + 1) * HW + pp];
            float x2 = xb[(c + 2) * HW + pp];
            float x3 = xb[(c + 3) * HW + pp];
            float d0 = qv.x - x0;
            float d1 = qv.y - x1;
            float d2 = qv.z - x2;
            float d3 = qv.w - x3;
            lsum += d0 * d0 + d1 * d1 + d2 * d2 + d3 * d3;
            ob[(c + 0) * HW + pp] = x0 + d0;    // reference rounding: x + (q - x)
            ob[(c + 1) * HW + pp] = x1 + d1;
            ob[(c + 2) * HW + pp] = x2 + d2;
            ob[(c + 3) * HW + pp] = x3 + d3;
        }
    }
    for (int off = 32; off > 0; off >>= 1) lsum += __shfl_down(lsum, off, 64);
    if (lane == 0) atomicAdd(loss_acc, lsum);

    __syncthreads();
    if (t < KEMB) {
        int v = hist[t];
        if (v) atomicAdd(&counts[t], v);
    }

    // ---- Fused finalize: last block to arrive computes perplexity + loss.
    __threadfence();
    __syncthreads();
    if (t == 0) lastflag = (atomicAdd(done_ctr, 1) == 511) ? 1 : 0;
    __syncthreads();
    if (lastflag) {
        if (t < KEMB) {
            int cnt = atomicAdd(&counts[t], 0);   // device-coherent read
            float pa = (float)cnt / (float)NPIX;
            float v = pa * logf(pa + 1e-10f);
#pragma unroll
            for (int off = 1; off <= 32; off <<= 1) v += __shfl_xor(v, off, 64);
            if ((t & 63) == 0) part[t >> 6] = v;
        }
        __syncthreads();
        if (t == 0) {
            float s = 0.f;
#pragma unroll
            for (int i = 0; i < 8; ++i) s += part[i];
            dout[PERP_OFF] = expf(-s);
            dout[0] = 0.25f * atomicAdd(loss_acc, 0.0f) / 8388608.0f;
        }
    }
}

extern "C" void kernel_launch(void* const* d_in, const int* in_sizes, int n_in,
                              void* d_out, int out_size, void* d_ws, size_t ws_size,
                              hipStream_t stream) {
    const float* in  = (const float*)d_in[0];   // 8388608 elems
    const float* emb = (const float*)d_in[1];   // 32768 elems
    float* dout = (float*)d_out;
    int*   counts   = (int*)d_ws;
    float* hnorms   = (float*)((char*)d_ws + 2048);
    float* loss_acc = (float*)((char*)d_ws + 4096);
    int*   done_ctr = (int*)((char*)d_ws + 4160);
    unsigned short* eh_t = (unsigned short*)((char*)d_ws + 8192);
    unsigned short* el_t = eh_t + KEMB * DDIM;   // 64 KB scaled-l table

    vq_init<<<512, 64, 0, stream>>>(emb, counts, hnorms, loss_acc, done_ctr, eh_t, el_t);
    vq_main<<<512, 1024, 0, stream>>>(in, emb, eh_t, el_t, hnorms, counts, loss_acc, done_ctr, dout);
}

// Round 3
// 266.705 us; speedup vs baseline: 1.7968x; 1.4447x over previous
//
#include <hip/hip_runtime.h>
#include <hip/hip_fp16.h>
#include <math.h>

// Problem constants
#define NPIX   131072      // B*H*W = 32*64*64
#define KEMB   512
#define DDIM   64
#define HW     4096        // H*W
#define BSTRIDE 262144     // C*H*W

// d_out flat layout (float32): [loss(1) | out(8388608) | perplexity(1) | indices(131072)]
#define OUT_OFF  1
#define PERP_OFF 8388609
#define IDX_OFF  8388610

typedef __attribute__((ext_vector_type(8))) _Float16 f16x8;    // MFMA A/B frag (4 VGPRs)
typedef __attribute__((ext_vector_type(4))) float f32x4;       // MFMA C/D frag

// ws layout: [0,2048) int counts | [2048,4096) float hnorms | [4096] loss |
//            [4160] done_ctr | [8192,73728) eh_t (f16 high, frag-linear, 64KB) |
//            [73728,139264) el_t (f16 low pre-scaled by 2^11, frag-linear, 64KB)
//
// frag-linear: idx = ct*1024 + ks*512 + lane*8 + j (f16 units), so a wave's
// tile-(ct,ks) fragment load is a contiguous, coalesced 1KB global read.
//
// 2-split f16 scheme (R2-proven, absmax 0): x = h + l/2048 + r, |r|<=2^-22|x|.
// l is pre-scaled by 2^11 (exact pow2) to stay in f16 normal range. Products
// kept: hh + (h*l' + l'*h)/2048; dropped terms ~3e-5 absolute, decided away by
// the exact fp32 top-2 rescore (verbatim from the passing kernel).
//
// R2 POST-MORTEM baked in here: __launch_bounds__(1024,8)'s 64-reg unified cap
// forced in-K-loop scratch spills (VGPR=32, +80MB HBM, MfmaUtil 3%). Fix: no
// LDS table at all (both tables stream from the L2-resident 128KB workspace),
// so blocks can be small: 256 thr, reg cap 102 >> demand ~86, 20 waves/CU.
__global__ void vq_init(const float* __restrict__ emb, int* __restrict__ counts,
                        float* __restrict__ hnorms, float* __restrict__ loss_acc,
                        int* __restrict__ done_ctr,
                        unsigned short* __restrict__ eh_t,
                        unsigned short* __restrict__ el_t) {
    const int k = blockIdx.x;             // code
    const int c = threadIdx.x;            // channel
    const int ct = k >> 4, col = k & 15;
    const int ks = c >> 5, quad = (c >> 3) & 3, j = c & 7;
    float x = emb[k * DDIM + c];
    _Float16 h = (_Float16)x;             // v_cvt_f16_f32, RTNE
    float r1 = x - (float)h;              // exact (Sterbenz)
    _Float16 l = (_Float16)(r1 * 2048.0f);
    const int dst = ct * 1024 + ks * 512 + (quad * 16 + col) * 8 + j;
    ((_Float16*)eh_t)[dst] = h;
    ((_Float16*)el_t)[dst] = l;
    float s = x * x;
#pragma unroll
    for (int off = 1; off <= 32; off <<= 1) s += __shfl_xor(s, off, 64);
    if (c == 0) {
        hnorms[k] = 0.5f * s;
        counts[k] = 0;
        if (k == 0) { *loss_acc = 0.f; *done_ctr = 0; }
    }
}

// 1024 blocks x 256 threads (4 waves), 32 px/wave. No LDS tables -> LDS 4.6KB.
// Reg cap 102 (launch_bounds 256,5): 5 waves/SIMD = 20 waves/CU if regs <=102.
// K-loop streams Ah/Al fragments straight from L2 (coalesced 1KB/wave loads);
// barrier-free after the tiny prologue sync. Finalize fused via ticket.
__global__ __launch_bounds__(256, 5) void vq_main(
    const float* __restrict__ in, const float* __restrict__ emb,
    const unsigned short* __restrict__ eh_t, const unsigned short* __restrict__ el_t,
    const float* __restrict__ hnorms, int* __restrict__ counts,
    float* __restrict__ loss_acc, int* __restrict__ done_ctr,
    float* __restrict__ dout)
{
    __shared__ __align__(16) float hn_lds[KEMB];                 // 2 KB
    __shared__ int hist[KEMB];                                   // 2 KB
    __shared__ float part[4];
    __shared__ int lastflag;

    const int t    = threadIdx.x;         // 0..255
    const int lane = t & 63;
    const int wv   = t >> 6;              // wave id 0..3
    const int quad = lane >> 4;
    const int col  = lane & 15;
    const int b    = blockIdx.x >> 5;                        // 32 blocks per image
    const int p0   = ((blockIdx.x & 31) << 7) | (wv << 5);   // first of this wave's 32 px
    const float* xb = in + b * BSTRIDE;

    hist[t] = 0; hist[t + 256] = 0;
    if (t < 128) ((float4*)hn_lds)[t] = ((const float4*)hnorms)[t];

    // ---- Build x B-fragments: B[n=col][k=quad*8+j], xh/xl[ptile][kstep]
    f16x8 xh[2][2], xl[2][2];
#pragma unroll
    for (int tt = 0; tt < 2; ++tt) {
#pragma unroll
        for (int s = 0; s < 2; ++s) {
            const int ppb = p0 + tt * 16 + col;
            const int c0  = s * 32 + quad * 8;
            f16x8 vh, vl;
#pragma unroll
            for (int j = 0; j < 8; ++j) {
                float x = xb[(c0 + j) * HW + ppb];
                _Float16 h = (_Float16)x;
                float r1 = x - (float)h;
                vh[j] = h;
                vl[j] = (_Float16)(r1 * 2048.0f);
            }
            xh[tt][s] = vh; xl[tt][s] = vl;
        }
    }

    __syncthreads();   // hist/hn ready; K-loop below is barrier-free

    // ---- K-loop over 32 code tiles; Ah/Al stream from L2-resident tables
    float v1[2], v2[2]; int k1[2], k2[2];
#pragma unroll
    for (int tt = 0; tt < 2; ++tt) {
        v1[tt] = 3.402823466e38f; v2[tt] = 3.402823466e38f; k1[tt] = 0; k2[tt] = 0;
    }
    const char* hp = (const char*)eh_t + lane * 16;
    const char* lp = (const char*)el_t + lane * 16;

    for (int ct = 0; ct < 32; ++ct) {
        const f16x8 Ah0 = *(const f16x8*)(hp);
        const f16x8 Ah1 = *(const f16x8*)(hp + 1024);
        const f16x8 Al0 = *(const f16x8*)(lp);
        const f16x8 Al1 = *(const f16x8*)(lp + 1024);
        hp += 2048; lp += 2048;

        // Per pixel-tile: acc_h = hh terms, acc_l = 2^11*(h*l + l*h) terms.
        // MFMA accumulation order bitwise == R2's passing kernel.
        f32x4 a0h = (f32x4){0.f, 0.f, 0.f, 0.f};
        f32x4 a0l = (f32x4){0.f, 0.f, 0.f, 0.f};
        f32x4 a1h = (f32x4){0.f, 0.f, 0.f, 0.f};
        f32x4 a1l = (f32x4){0.f, 0.f, 0.f, 0.f};
        a0h = __builtin_amdgcn_mfma_f32_16x16x32_f16(Ah0, xh[0][0], a0h, 0, 0, 0);
        a0l = __builtin_amdgcn_mfma_f32_16x16x32_f16(Ah0, xl[0][0], a0l, 0, 0, 0);
        a0l = __builtin_amdgcn_mfma_f32_16x16x32_f16(Al0, xh[0][0], a0l, 0, 0, 0);
        a1h = __builtin_amdgcn_mfma_f32_16x16x32_f16(Ah0, xh[1][0], a1h, 0, 0, 0);
        a1l = __builtin_amdgcn_mfma_f32_16x16x32_f16(Ah0, xl[1][0], a1l, 0, 0, 0);
        a1l = __builtin_amdgcn_mfma_f32_16x16x32_f16(Al0, xh[1][0], a1l, 0, 0, 0);
        a0h = __builtin_amdgcn_mfma_f32_16x16x32_f16(Ah1, xh[0][1], a0h, 0, 0, 0);
        a0l = __builtin_amdgcn_mfma_f32_16x16x32_f16(Ah1, xl[0][1], a0l, 0, 0, 0);
        a0l = __builtin_amdgcn_mfma_f32_16x16x32_f16(Al1, xh[0][1], a0l, 0, 0, 0);
        a1h = __builtin_amdgcn_mfma_f32_16x16x32_f16(Ah1, xh[1][1], a1h, 0, 0, 0);
        a1l = __builtin_amdgcn_mfma_f32_16x16x32_f16(Ah1, xl[1][1], a1l, 0, 0, 0);
        a1l = __builtin_amdgcn_mfma_f32_16x16x32_f16(Al1, xh[1][1], a1l, 0, 0, 0);

        const f32x4 hn = *(const f32x4*)&hn_lds[ct * 16 + quad * 4];
#pragma unroll
        for (int r = 0; r < 4; ++r) {
            const int kk = ct * 16 + quad * 4 + r;
            float sc = hn[r] - (a0h[r] + a0l[r] * 4.8828125e-4f);  // + acc_l/2048
            if (sc < v1[0]) { v2[0] = v1[0]; k2[0] = k1[0]; v1[0] = sc; k1[0] = kk; }
            else if (sc < v2[0]) { v2[0] = sc; k2[0] = kk; }
            sc = hn[r] - (a1h[r] + a1l[r] * 4.8828125e-4f);
            if (sc < v1[1]) { v2[1] = v1[1]; k2[1] = k1[1]; v1[1] = sc; k1[1] = kk; }
            else if (sc < v2[1]) { v2[1] = sc; k2[1] = kk; }
        }
    }

    // Cross-quad top-2 merge (lanes l, l^16, l^32 share pixel-col) — R0 verbatim
#pragma unroll
    for (int tt = 0; tt < 2; ++tt) {
#pragma unroll
        for (int off = 16; off <= 32; off <<= 1) {
            float w1 = __shfl_xor(v1[tt], off, 64); int j1 = __shfl_xor(k1[tt], off, 64);
            float w2 = __shfl_xor(v2[tt], off, 64); int j2 = __shfl_xor(k2[tt], off, 64);
            bool aF = (v1[tt] < w1) || (v1[tt] == w1 && k1[tt] < j1);
            float t1 = aF ? v1[tt] : w1;  int u1 = aF ? k1[tt] : j1;
            float tl = aF ? w1 : v1[tt];  int ul = aF ? j1 : k1[tt];      // loser of firsts
            bool bS = (v2[tt] < w2) || (v2[tt] == w2 && k2[tt] < j2);
            float tc = bS ? v2[tt] : w2;  int uc = bS ? k2[tt] : j2;      // better of seconds
            bool lS = (tl < tc) || (tl == tc && ul < uc);
            v1[tt] = t1; k1[tt] = u1;
            v2[tt] = lS ? tl : tc; k2[tt] = lS ? ul : uc;
        }
    }

    // Pixel q = lane&31; lanes l and l+32 handle the same pixel (tt = (l>>4)&1).
    const int q    = lane & 31;
    const int pp   = p0 + q;
    const int tsel = (lane >> 4) & 1;
    const int kA = tsel ? k1[1] : k1[0];
    const int kB = tsel ? k2[1] : k2[0];

    // Exact fp32 rescore, split: lanes<32 score kA, lanes>=32 score kB.
    // Streaming x loads — ops and order bitwise == the passing kernels.
    const int kMine = (lane < 32) ? kA : kB;
    const float4* eM = (const float4*)(emb + kMine * DDIM);
    float a0 = hn_lds[kMine], a1 = 0.f, a2 = 0.f, a3 = 0.f;
#pragma unroll
    for (int i = 0; i < 16; ++i) {
        float4 ea = eM[i];
        const int c = i * 4;
        float x0 = xb[(c + 0) * HW + pp];
        float x1 = xb[(c + 1) * HW + pp];
        float x2 = xb[(c + 2) * HW + pp];
        float x3 = xb[(c + 3) * HW + pp];
        a0 = fmaf(-x0, ea.x, a0);
        a1 = fmaf(-x1, ea.y, a1);
        a2 = fmaf(-x2, ea.z, a2);
        a3 = fmaf(-x3, ea.w, a3);
    }
    const float dMine = (a0 + a1) + (a2 + a3);
    const float dOth  = __shfl_xor(dMine, 32, 64);
    const float dA = (lane < 32) ? dMine : dOth;
    const float dB = (lane < 32) ? dOth  : dMine;
    const int myk = (dB < dA || (dB == dA && kB < kA)) ? kB : kA;

    float lsum = 0.f;
    if (lane < 32) {
        dout[IDX_OFF + b * HW + pp] = (float)myk;
        atomicAdd(&hist[myk], 1);
        const float4* qrow = (const float4*)(emb + myk * DDIM);
        float* ob = dout + OUT_OFF + b * BSTRIDE;
#pragma unroll
        for (int i = 0; i < 16; ++i) {
            float4 qv = qrow[i];
            const int c = i * 4;
            float x0 = xb[(c + 0) * HW + pp];   // L1-warm reload (just read above)
            float x1 = xb[(c + 1) * HW + pp];
            float x2 = xb[(c + 2) * HW + pp];
            float x3 = xb[(c + 3) * HW + pp];
            float d0 = qv.x - x0;
            float d1 = qv.y - x1;
            float d2 = qv.z - x2;
            float d3 = qv.w - x3;
            lsum += d0 * d0 + d1 * d1 + d2 * d2 + d3 * d3;
            ob[(c + 0) * HW + pp] = x0 + d0;    // reference rounding: x + (q - x)
            ob[(c + 1) * HW + pp] = x1 + d1;
            ob[(c + 2) * HW + pp] = x2 + d2;
            ob[(c + 3) * HW + pp] = x3 + d3;
        }
    }
    for (int off = 32; off > 0; off >>= 1) lsum += __shfl_down(lsum, off, 64);
    if (lane == 0) atomicAdd(loss_acc, lsum);

    __syncthreads();
    {
        int v = hist[t];
        if (v) atomicAdd(&counts[t], v);
        v = hist[t + 256];
        if (v) atomicAdd(&counts[t + 256], v);
    }

    // ---- Fused finalize: last block to arrive computes perplexity + loss.
    __threadfence();
    __syncthreads();
    if (t == 0) lastflag = (atomicAdd(done_ctr, 1) == 1023) ? 1 : 0;
    __syncthreads();
    if (lastflag) {
        float v = 0.f;
#pragma unroll
        for (int kk = 0; kk < 2; ++kk) {
            int cnt = atomicAdd(&counts[t + kk * 256], 0);   // device-coherent read
            float pa = (float)cnt / (float)NPIX;
            v += pa * logf(pa + 1e-10f);
        }
#pragma unroll
        for (int off = 1; off <= 32; off <<= 1) v += __shfl_xor(v, off, 64);
        if (lane == 0) part[wv] = v;
        __syncthreads();
        if (t == 0) {
            float s = part[0] + part[1] + part[2] + part[3];
            dout[PERP_OFF] = expf(-s);
            dout[0] = 0.25f * atomicAdd(loss_acc, 0.0f) / 8388608.0f;
        }
    }
}

extern "C" void kernel_launch(void* const* d_in, const int* in_sizes, int n_in,
                              void* d_out, int out_size, void* d_ws, size_t ws_size,
                              hipStream_t stream) {
    const float* in  = (const float*)d_in[0];   // 8388608 elems
    const float* emb = (const float*)d_in[1];   // 32768 elems
    float* dout = (float*)d_out;
    int*   counts   = (int*)d_ws;
    float* hnorms   = (float*)((char*)d_ws + 2048);
    float* loss_acc = (float*)((char*)d_ws + 4096);
    int*   done_ctr = (int*)((char*)d_ws + 4160);
    unsigned short* eh_t = (unsigned short*)((char*)d_ws + 8192);
    unsigned short* el_t = eh_t + KEMB * DDIM;   // 64 KB scaled-l table

    vq_init<<<512, 64, 0, stream>>>(emb, counts, hnorms, loss_acc, done_ctr, eh_t, el_t);
    vq_main<<<1024, 256, 0, stream>>>(in, emb, eh_t, el_t, hnorms, counts, loss_acc, done_ctr, dout);
}